// Round 1
// baseline (389.094 us; speedup 1.0000x reference)
//
#include <hip/hip_runtime.h>
#include <cstddef>

#define NCLASS 64

__global__ __launch_bounds__(64)
void crf_nll_kernel(const float* __restrict__ logits,
                    const float* __restrict__ trans,
                    const float* __restrict__ init_alphas,
                    const int*  __restrict__ lengths,
                    const int*  __restrict__ tags,
                    float* __restrict__ out,
                    int N, int T)
{
    const int n = blockIdx.x;
    const int lane = threadIdx.x;          // 0..63, owns row `lane`
    const float* lg = logits + (size_t)n * T * NCLASS;
    const int len = lengths[n];            // in [2, T]

    __shared__ __align__(16) float p_lds[2][NCLASS];

    // E row for this lane: exp(trans[lane][j]) -> 64 VGPRs, loaded once
    float E[NCLASS];
    #pragma unroll
    for (int j = 0; j < NCLASS; ++j)
        E[j] = __expf(trans[lane * NCLASS + j]);

    // alpha_0 = init_alphas + logits[0]
    float alpha = init_alphas[lane] + lg[lane];

    // depth-2 prefetch of logits rows (coalesced 256B/step)
    float f0 = (len > 1) ? lg[1 * NCLASS + lane] : 0.f;
    float f1 = (len > 2) ? lg[2 * NCLASS + lane] : 0.f;

    int buf = 0;
    for (int t = 1; t < len; ++t) {
        // stabilizer: alpha[0] (spread across lanes bounded ~12, exp-safe)
        const float c = __shfl(alpha, 0);
        const float p = __expf(alpha - c);
        p_lds[buf][lane] = p;
        __syncthreads();

        const float4* p4 = reinterpret_cast<const float4*>(p_lds[buf]);
        float a0 = 0.f, a1 = 0.f, a2 = 0.f, a3 = 0.f;
        #pragma unroll
        for (int jj = 0; jj < 16; ++jj) {
            const float4 pv = p4[jj];            // broadcast read, conflict-free
            a0 = __fmaf_rn(E[4*jj+0], pv.x, a0);
            a1 = __fmaf_rn(E[4*jj+1], pv.y, a1);
            a2 = __fmaf_rn(E[4*jj+2], pv.z, a2);
            a3 = __fmaf_rn(E[4*jj+3], pv.w, a3);
        }
        const float dot = (a0 + a1) + (a2 + a3);

        alpha = f0 + c + __logf(dot);            // new alpha for row `lane`

        f0 = f1;
        if (t + 2 < len) f1 = lg[(t + 2) * NCLASS + lane];
        buf ^= 1;
    }

    // logZ at the true length: c2 + log(sum_j exp(alpha_j - c2))
    const float c2 = __shfl(alpha, 0);
    float p2 = __expf(alpha - c2);
    #pragma unroll
    for (int off = 32; off; off >>= 1) p2 += __shfl_xor(p2, off);
    const float logZ = c2 + __logf(p2);

    // gold score: first + sum_{t=1}^{len-1} trans[tag_t, tag_{t-1}] + logit[t, tag_t]
    const int* tg = tags + (size_t)n * T;
    float g = 0.f;
    for (int t = 1 + lane; t < len; t += 64) {
        const int cur = tg[t];
        const int prv = tg[t - 1];
        g += trans[cur * NCLASS + prv] + lg[t * NCLASS + cur];
    }
    #pragma unroll
    for (int off = 32; off; off >>= 1) g += __shfl_xor(g, off);

    if (lane == 0) {
        const int t0 = tg[0];
        const float gold = init_alphas[t0] + lg[t0] + g;
        out[n] = logZ - gold;
    }
}

extern "C" void kernel_launch(void* const* d_in, const int* in_sizes, int n_in,
                              void* d_out, int out_size, void* d_ws, size_t ws_size,
                              hipStream_t stream)
{
    const float* logits = (const float*)d_in[0];   // [N][T][C] f32
    const float* trans  = (const float*)d_in[1];   // [C][C]    f32
    const float* inita  = (const float*)d_in[2];   // [C]       f32
    const int*   lens   = (const int*)d_in[3];     // [N]       i32
    const int*   tags   = (const int*)d_in[4];     // [N][T]    i32
    float*       out    = (float*)d_out;           // [N]       f32

    const int N = 512, T = 1024;
    crf_nll_kernel<<<N, 64, 0, stream>>>(logits, trans, inita, lens, tags, out, N, T);
}